// Round 10
// baseline (86.888 us; speedup 1.0000x reference)
//
#include <hip/hip_runtime.h>
#include <hip/hip_fp16.h>

// NegSamplingWord2Vec, L2-sharded gather:
//   losses[b] = sum_w mask(o_idx!=PAD) * ( softplus(-dot(c,o_w)) +
//                                          sum_k softplus(dot(c,neg_wk)) )
//
// R8 conclusion: gather is pinned at the L3->L2 random-line ceiling
// (~3.0-3.4 TB/s); more MLP does nothing. This version makes table rows
// L2-HITS: the f16 table is split into 8 shards of ~12.5K rows (3.2 MB,
// fits a 4MB per-XCD L2); grid = (chunk, shard) with shard = blockIdx%8,
// which round-robins onto XCDs, so each XCD re-reads only its own shard.
// Shard misassignment (if the mapping assumption is wrong) costs only
// locality, never correctness.
//
// K1  : f32 outside table -> f16 table in ws          (streaming)
// K1b : f32 used center rows -> f16 [batch][128] ws   (small)
// K2  : bucketize 901K refs into per-(chunk,shard) lists, deterministic
// K3  : per-shard gather + v_dot2_f32_f16 + softplus, ordered accum
// K4  : out[b] = sum over 8 shard partials (fixed order)
// No FP atomics anywhere -> bit-deterministic.

#define D_DIM   128
#define W_CTX   10
#define K_NEG   10
#define CHUNK   32            // batch elems per chunk
#define CAP     688           // entries per (chunk,shard) list (avg 440, +12 sigma)
#define NSHARD  8
#define BLK     256

typedef _Float16 half2v __attribute__((ext_vector_type(2)));

__device__ __forceinline__ float fast_softplus(float x) {
    return fmaxf(x, 0.0f) + __logf(1.0f + __expf(-fabsf(x)));
}

#if __has_builtin(__builtin_amdgcn_fdot2)
__device__ __forceinline__ float dot2acc(unsigned int a, unsigned int b, float c) {
    return __builtin_amdgcn_fdot2(__builtin_bit_cast(half2v, a),
                                  __builtin_bit_cast(half2v, b), c, false);
}
#else
__device__ __forceinline__ float dot2acc(unsigned int a, unsigned int b, float c) {
    c = fmaf(__half2float(__ushort_as_half((unsigned short)(a & 0xffff))),
             __half2float(__ushort_as_half((unsigned short)(b & 0xffff))), c);
    c = fmaf(__half2float(__ushort_as_half((unsigned short)(a >> 16))),
             __half2float(__ushort_as_half((unsigned short)(b >> 16))), c);
    return c;
}
#endif

__device__ __forceinline__ unsigned int pack2h(float x, float y) {
    unsigned int lo = __half_as_ushort(__float2half(x));
    unsigned int hi = __half_as_ushort(__float2half(y));
    return lo | (hi << 16);
}

// ---- K1: f32 table -> f16 table (8 elems / thread) ----
__global__ __launch_bounds__(BLK) void cvt_table_f16(
    const float4* __restrict__ src, uint4* __restrict__ dst, int n8)
{
    const int i = blockIdx.x * BLK + threadIdx.x;
    if (i >= n8) return;
    const float4 a = src[i * 2];
    const float4 b = src[i * 2 + 1];
    uint4 o;
    o.x = pack2h(a.x, a.y);
    o.y = pack2h(a.z, a.w);
    o.z = pack2h(b.x, b.y);
    o.w = pack2h(b.z, b.w);
    dst[i] = o;
}

// ---- K1b: gather-convert the used center rows -> f16 [batch][128] ----
__global__ __launch_bounds__(BLK) void cvt_centers_f16(
    const float* __restrict__ cen, const int* __restrict__ cidx,
    unsigned int* __restrict__ dst, int batch)
{
    const int wave = threadIdx.x >> 6, lane = threadIdx.x & 63;
    const int b = blockIdx.x * 4 + wave;
    if (b >= batch) return;
    const int ci = cidx[b];
    const float2 v = *reinterpret_cast<const float2*>(
        cen + (size_t)ci * D_DIM + lane * 2);
    dst[(size_t)b * (D_DIM / 2) + lane] = pack2h(v.x, v.y);
}

// ---- K2: bucketize refs into per-(chunk,shard) lists, deterministic ----
// entry = row(17b) | elem(5b)<<17 | sign(1b)<<22  (sign=1: negative sample)
__global__ __launch_bounds__(64) void bucketize(
    const int* __restrict__ owi, const int* __restrict__ neg,
    unsigned int* __restrict__ ents, int* __restrict__ cnts,
    float inv_shard)
{
    const int c = blockIdx.x;
    const int t = threadIdx.x;

    __shared__ unsigned short s_cnt[CHUNK][NSHARD];
    __shared__ unsigned short s_pos[CHUNK][NSHARD];

    if (t < CHUNK)
        for (int x = 0; x < NSHARD; ++x) s_cnt[t][x] = 0;
    __syncthreads();

    // pass 1: count (thread t owns elem t; serial, deterministic)
    if (t < CHUNK) {
        const int b = c * CHUNK + t;
        const int* nb = neg + (size_t)b * (W_CTX * K_NEG);
        for (int w = 0; w < W_CTX; ++w) {
            const int oi = owi[b * W_CTX + w];
            if (oi == 0) continue;                       // masked group
            int x = (int)((float)oi * inv_shard); x = x > 7 ? 7 : x;
            s_cnt[t][x]++;
            for (int k = 0; k < K_NEG; ++k) {
                const int r = nb[w * K_NEG + k];
                int y = (int)((float)r * inv_shard); y = y > 7 ? 7 : y;
                s_cnt[t][y]++;
            }
        }
    }
    __syncthreads();

    // exclusive scan over elems, per shard (threads 0..7, serial = fixed order)
    if (t < NSHARD) {
        int run = 0;
        for (int e = 0; e < CHUNK; ++e) {
            const int k = s_cnt[e][t];
            s_pos[e][t] = (unsigned short)run;
            run += k;
        }
        cnts[c * NSHARD + t] = run < CAP ? run : CAP;
    }
    __syncthreads();

    // pass 2: emit at deterministic positions
    if (t < CHUNK) {
        const int b = c * CHUNK + t;
        const int* nb = neg + (size_t)b * (W_CTX * K_NEG);
        for (int w = 0; w < W_CTX; ++w) {
            const int oi = owi[b * W_CTX + w];
            if (oi == 0) continue;
            {
                int x = (int)((float)oi * inv_shard); x = x > 7 ? 7 : x;
                const int p = s_pos[t][x]++;
                if (p < CAP)
                    ents[((size_t)c * NSHARD + x) * CAP + p] =
                        (unsigned int)oi | ((unsigned int)t << 17);
            }
            for (int k = 0; k < K_NEG; ++k) {
                const int r = nb[w * K_NEG + k];
                int y = (int)((float)r * inv_shard); y = y > 7 ? 7 : y;
                const int p = s_pos[t][y]++;
                if (p < CAP)
                    ents[((size_t)c * NSHARD + y) * CAP + p] =
                        (unsigned int)r | ((unsigned int)t << 17) | (1u << 22);
            }
        }
    }
}

// ---- K3: per-shard gather + dot + softplus ----
__global__ __launch_bounds__(BLK) void shard_gather(
    const unsigned short* __restrict__ tab,   // f16 [n_tok][128]
    const unsigned int*   __restrict__ cen,   // f16 [batch][64] (as uint)
    const unsigned int*   __restrict__ ents,
    const int*            __restrict__ cnts,
    float*                __restrict__ parts)
{
    const int bid = blockIdx.x;
    const int c = bid >> 3, x = bid & 7;      // shard = bid%8 -> XCD affinity
    const int tid = threadIdx.x;
    const int g  = tid >> 4;                  // 16 groups of 16 lanes
    const int gl = tid & 15;

    __shared__ unsigned int lds_c[CHUNK][D_DIM / 2];   // 8 KB f16 centers
    __shared__ float s_acc[16][CHUNK];                 // 2 KB

    for (int i = tid; i < 16 * CHUNK; i += BLK)
        (&s_acc[0][0])[i] = 0.0f;

    // stage 32 center rows (256B each): 8 threads/row x 32B
    {
        const int e = tid >> 3, q = tid & 7;
        const uint4* src = reinterpret_cast<const uint4*>(
            cen + ((size_t)(c * CHUNK + e)) * (D_DIM / 2)) + q * 2;
        const uint4 v0 = src[0];
        const uint4 v1 = src[1];
        uint4* d = reinterpret_cast<uint4*>(&lds_c[e][0]) + q * 2;
        d[0] = v0; d[1] = v1;
    }
    __syncthreads();

    const int count = cnts[c * NSHARD + x];
    const unsigned int* list = ents + ((size_t)c * NSHARD + x) * CAP;
    const int npass = (count + 15) >> 4;

    float acc = 0.0f;
    int cur = -1;
    for (int p = 0; p < npass; ++p) {
        const int pos = p * 16 + g;
        if (pos < count) {
            const unsigned int e_ = list[pos];       // same addr in group: broadcast
            const int row  = (int)(e_ & 0x1FFFFu);
            const int elem = (int)((e_ >> 17) & 31u);
            const int sign = (int)((e_ >> 22) & 1u);

            const uint4 tv = *(reinterpret_cast<const uint4*>(
                tab + (size_t)row * D_DIM) + gl);    // shard row: L2 hit
            const uint4 cv = *(reinterpret_cast<const uint4*>(&lds_c[elem][0]) + gl);

            float s = dot2acc(tv.x, cv.x, 0.0f);
            s = dot2acc(tv.y, cv.y, s);
            s = dot2acc(tv.z, cv.z, s);
            s = dot2acc(tv.w, cv.w, s);
            s += __shfl_xor(s, 8, 64);
            s += __shfl_xor(s, 4, 64);
            s += __shfl_xor(s, 2, 64);
            s += __shfl_xor(s, 1, 64);

            const float term = fast_softplus(sign ? s : -s);
            if (elem != cur) {                       // list is elem-ordered
                if (cur >= 0 && gl == 0) s_acc[g][cur] += acc;
                cur = elem; acc = 0.0f;
            }
            acc += term;
        }
    }
    if (cur >= 0 && gl == 0) s_acc[g][cur] += acc;
    __syncthreads();

    if (tid < CHUNK) {
        float tsum = 0.0f;
        for (int gg = 0; gg < 16; ++gg) tsum += s_acc[gg][tid];   // fixed order
        parts[((size_t)c * NSHARD + x) * CHUNK + tid] = tsum;
    }
}

// ---- K4: combine shard partials (fixed order) ----
__global__ __launch_bounds__(BLK) void reduce_out(
    const float* __restrict__ parts, float* __restrict__ out, int batch)
{
    const int b = blockIdx.x * BLK + threadIdx.x;
    if (b >= batch) return;
    const int c = b >> 5, e = b & 31;
    float t = 0.0f;
#pragma unroll
    for (int x = 0; x < NSHARD; ++x)
        t += parts[((size_t)c * NSHARD + x) * CHUNK + e];
    out[b] = t;
}

// ---- fallback: round-3 proven f32 kernel ----
#define NROWS   110
#define NROWS_P 112
#define NPASS   7
__global__ __launch_bounds__(BLK) void w2v_f32_kernel(
    const float* __restrict__ center_vectors,
    const float* __restrict__ outside_vectors,
    const int*   __restrict__ center_word_index,
    const int*   __restrict__ outside_word_indices,
    const int*   __restrict__ negative_samples,
    float*       __restrict__ out)
{
    const int b    = blockIdx.x;
    const int tid  = threadIdx.x;
    const int wave = tid >> 6;
    const int lane = tid & 63;
    const int grp  = lane >> 4;
    const int gl   = lane & 15;

    __shared__ int   s_idx[NROWS_P];
    __shared__ float s_part[4];

    if (tid < W_CTX) {
        s_idx[tid * 11] = outside_word_indices[b * W_CTX + tid];
    } else if (tid >= 16 && tid < 16 + W_CTX * K_NEG) {
        const int r = tid - 16;
        const int w = r / K_NEG;
        const int j = r - w * K_NEG;
        s_idx[w * 11 + 1 + j] = negative_samples[b * W_CTX * K_NEG + r];
    } else if (tid >= 128 && tid < 128 + (NROWS_P - NROWS)) {
        s_idx[NROWS + (tid - 128)] = 0;
    }
    __syncthreads();

    const int ci = center_word_index[b];
    const float4* cp = reinterpret_cast<const float4*>(
        center_vectors + (size_t)ci * D_DIM);
    const float4 c0 = cp[gl];
    const float4 c1 = cp[16 + gl];

    float acc = 0.0f;
#pragma unroll
    for (int p = 0; p < NPASS; ++p) {
        const int r = p * 16 + wave * 4 + grp;
        const int w = r / 11;
        const int j = r - w * 11;
        const int idx = s_idx[r];
        const int oi = s_idx[w * 11];
        const float cf = (oi != 0) ? ((j == 0) ? -1.0f : 1.0f) : 0.0f;

        const float4* rp = reinterpret_cast<const float4*>(
            outside_vectors + (size_t)idx * D_DIM);
        const float4 a0 = rp[gl];
        const float4 a1 = rp[16 + gl];

        float s = c0.x * a0.x;
        s = fmaf(c0.y, a0.y, s);
        s = fmaf(c0.z, a0.z, s);
        s = fmaf(c0.w, a0.w, s);
        s = fmaf(c1.x, a1.x, s);
        s = fmaf(c1.y, a1.y, s);
        s = fmaf(c1.z, a1.z, s);
        s = fmaf(c1.w, a1.w, s);

        s += __shfl_xor(s, 8, 64);
        s += __shfl_xor(s, 4, 64);
        s += __shfl_xor(s, 2, 64);
        s += __shfl_xor(s, 1, 64);

        acc += fabsf(cf) * fast_softplus(cf * s);
    }

    acc += __shfl_xor(acc, 16, 64);
    acc += __shfl_xor(acc, 32, 64);

    if (lane == 0) s_part[wave] = acc;
    __syncthreads();

    if (tid == 0)
        out[b] = s_part[0] + s_part[1] + s_part[2] + s_part[3];
}

extern "C" void kernel_launch(void* const* d_in, const int* in_sizes, int n_in,
                              void* d_out, int out_size, void* d_ws, size_t ws_size,
                              hipStream_t stream) {
    const float* center_vectors       = (const float*)d_in[0];
    const float* outside_vectors      = (const float*)d_in[1];
    const int*   center_word_index    = (const int*)d_in[2];
    const int*   outside_word_indices = (const int*)d_in[3];
    const int*   negative_samples     = (const int*)d_in[4];
    float*       out                  = (float*)d_out;

    const int batch = in_sizes[2];               // 8192
    const int n_tok = in_sizes[1] / D_DIM;       // 100000

    const int nchunk = batch / CHUNK;
    auto al = [](size_t v) { return (v + 255) & ~(size_t)255; };
    const size_t tab_b = al((size_t)n_tok * D_DIM * 2);
    const size_t cen_b = al((size_t)batch * D_DIM * 2);
    const size_t ent_b = al((size_t)nchunk * NSHARD * CAP * 4);
    const size_t cnt_b = al((size_t)nchunk * NSHARD * 4);
    const size_t par_b = al((size_t)nchunk * NSHARD * CHUNK * 4);
    const size_t need  = tab_b + cen_b + ent_b + cnt_b + par_b;

    if ((batch % CHUNK) == 0 && n_tok <= 131072 && ws_size >= need) {
        char* w = (char*)d_ws;
        unsigned short* tab  = (unsigned short*)w;              w += tab_b;
        unsigned int*   cen  = (unsigned int*)w;                w += cen_b;
        unsigned int*   ents = (unsigned int*)w;                w += ent_b;
        int*            cnts = (int*)w;                         w += cnt_b;
        float*          part = (float*)w;

        const float inv_shard = 1.0f / (float)((n_tok + NSHARD - 1) / NSHARD);

        const int n8 = n_tok * D_DIM / 8;
        cvt_table_f16<<<(n8 + BLK - 1) / BLK, BLK, 0, stream>>>(
            (const float4*)outside_vectors, (uint4*)tab, n8);
        cvt_centers_f16<<<(batch + 3) / 4, BLK, 0, stream>>>(
            center_vectors, center_word_index, cen, batch);
        bucketize<<<nchunk, 64, 0, stream>>>(
            outside_word_indices, negative_samples, ents, cnts, inv_shard);
        shard_gather<<<nchunk * NSHARD, BLK, 0, stream>>>(
            tab, cen, ents, cnts, part);
        reduce_out<<<(batch + BLK - 1) / BLK, BLK, 0, stream>>>(
            part, out, batch);
    } else {
        w2v_f32_kernel<<<batch, BLK, 0, stream>>>(
            center_vectors, outside_vectors, center_word_index,
            outside_word_indices, negative_samples, out);
    }
}

// Round 11
// 68.736 us; speedup vs baseline: 1.2641x; 1.2641x over previous
//
#include <hip/hip_runtime.h>
#include <hip/hip_fp16.h>

// NegSamplingWord2Vec, L2-sharded gather v2 (parallel bucketize, pipelined K3):
//   losses[b] = sum_w mask(o_idx!=PAD) * ( softplus(-dot(c,o_w)) +
//                                          sum_k softplus(dot(c,neg_wk)) )
//
// R10 post-mortem: bucketize was 38.5us (serial); K3 had a dependent
// list-load chain + 8-way LDS bank conflict on the center tile. Fixes:
//   K2: 256 active threads/chunk, LDS-staged refs, deterministic
//       count/scan/emit (predict ~2us).
//   K3: list staged to LDS; 4 rows in flight per 16-lane group; dummy-padded
//       list (weight 0) -> branch-free; center tile padded [32][68] ints to
//       break bank aliasing; accumulation s_acc[g][elem] by group-lane-0 only
//       (exclusive -> deterministic).
// Entry bits: row:0-16 | elem:17-21 | sign:22 | shard:23-25 | dummy:26.

#define D_DIM   128
#define W_CTX   10
#define K_NEG   10
#define CHUNK   32            // batch elems per chunk
#define REFS    (CHUNK * 110) // 3520 refs per chunk
#define CAP     704           // entries per (chunk,shard) list; 11*64, ~13 sigma
#define NSHARD  8
#define BLK     256
#define SENT    0xFFFFFFFFu
#define DUMMY   ((1u << 26) | (31u << 17))

typedef _Float16 half2v __attribute__((ext_vector_type(2)));

__device__ __forceinline__ float fast_softplus(float x) {
    return fmaxf(x, 0.0f) + __logf(1.0f + __expf(-fabsf(x)));
}

#if __has_builtin(__builtin_amdgcn_fdot2)
__device__ __forceinline__ float dot2acc(unsigned int a, unsigned int b, float c) {
    return __builtin_amdgcn_fdot2(__builtin_bit_cast(half2v, a),
                                  __builtin_bit_cast(half2v, b), c, false);
}
#else
__device__ __forceinline__ float dot2acc(unsigned int a, unsigned int b, float c) {
    c = fmaf(__half2float(__ushort_as_half((unsigned short)(a & 0xffff))),
             __half2float(__ushort_as_half((unsigned short)(b & 0xffff))), c);
    c = fmaf(__half2float(__ushort_as_half((unsigned short)(a >> 16))),
             __half2float(__ushort_as_half((unsigned short)(b >> 16))), c);
    return c;
}
#endif

__device__ __forceinline__ unsigned int pack2h(float x, float y) {
    unsigned int lo = __half_as_ushort(__float2half(x));
    unsigned int hi = __half_as_ushort(__float2half(y));
    return lo | (hi << 16);
}

// ---- K1: f32 table -> f16 table (8 elems / thread) ----
__global__ __launch_bounds__(BLK) void cvt_table_f16(
    const float4* __restrict__ src, uint4* __restrict__ dst, int n8)
{
    const int i = blockIdx.x * BLK + threadIdx.x;
    if (i >= n8) return;
    const float4 a = src[i * 2];
    const float4 b = src[i * 2 + 1];
    uint4 o;
    o.x = pack2h(a.x, a.y);
    o.y = pack2h(a.z, a.w);
    o.z = pack2h(b.x, b.y);
    o.w = pack2h(b.z, b.w);
    dst[i] = o;
}

// ---- K1b: gather-convert used center rows -> f16 [batch][128] ----
__global__ __launch_bounds__(BLK) void cvt_centers_f16(
    const float* __restrict__ cen, const int* __restrict__ cidx,
    unsigned int* __restrict__ dst, int batch)
{
    const int wave = threadIdx.x >> 6, lane = threadIdx.x & 63;
    const int b = blockIdx.x * 4 + wave;
    if (b >= batch) return;
    const int ci = cidx[b];
    const float2 v = *reinterpret_cast<const float2*>(
        cen + (size_t)ci * D_DIM + lane * 2);
    dst[(size_t)b * (D_DIM / 2) + lane] = pack2h(v.x, v.y);
}

// ---- K2: parallel deterministic bucketize ----
__global__ __launch_bounds__(BLK) void bucketize(
    const int* __restrict__ owi, const int* __restrict__ neg,
    unsigned int* __restrict__ ents, int* __restrict__ cnts,
    float inv_shard)
{
    const int c = blockIdx.x;
    const int t = threadIdx.x;
    const int b0 = c * CHUNK;

    __shared__ int          s_owi[CHUNK * W_CTX];     // 1.25 KB
    __shared__ unsigned int s_ref[REFS];              // 14 KB
    __shared__ int          s_cnt[NSHARD][CHUNK];     // 1 KB
    __shared__ int          s_pos[NSHARD][CHUNK];     // 1 KB

    // stage outside-word indices (coalesced)
    for (int i = t; i < CHUNK * W_CTX; i += BLK)
        s_owi[i] = owi[b0 * W_CTX + i];
    __syncthreads();

    // build packed refs (coalesced-ish neg loads)
    for (int i = t; i < REFS; i += BLK) {
        const int e = i / 110, j = i - e * 110;
        unsigned int v;
        if (j < W_CTX) {
            const int oi = s_owi[e * W_CTX + j];
            if (oi == 0) v = SENT;
            else {
                int sh = (int)((float)oi * inv_shard); sh = sh > 7 ? 7 : sh;
                v = (unsigned int)oi | ((unsigned int)e << 17) |
                    ((unsigned int)sh << 23);
            }
        } else {
            const int jj = j - W_CTX;
            const int w = jj / K_NEG;
            const int oi = s_owi[e * W_CTX + w];
            if (oi == 0) v = SENT;
            else {
                const int r = neg[(size_t)(b0 + e) * (W_CTX * K_NEG) + jj];
                int sh = (int)((float)r * inv_shard); sh = sh > 7 ? 7 : sh;
                v = (unsigned int)r | ((unsigned int)e << 17) | (1u << 22) |
                    ((unsigned int)sh << 23);
            }
        }
        s_ref[i] = v;
    }
    __syncthreads();

    // count: thread (e,s)
    {
        const int e = t >> 3, s = t & 7;
        int cnt = 0;
        for (int j = 0; j < 110; ++j) {
            const unsigned int v = s_ref[e * 110 + j];
            if (v != SENT && (int)((v >> 23) & 7u) == s) ++cnt;
        }
        s_cnt[s][e] = cnt;
    }
    __syncthreads();

    // exclusive scan per shard, fixed elem order
    if (t < NSHARD) {
        int run = 0;
        for (int e = 0; e < CHUNK; ++e) {
            s_pos[t][e] = run;
            run += s_cnt[t][e];
        }
        cnts[c * NSHARD + t] = run < CAP ? run : CAP;
    }
    __syncthreads();

    // emit at deterministic positions
    {
        const int e = t >> 3, s = t & 7;
        int pos = s_pos[s][e];
        unsigned int* dst = ents + ((size_t)c * NSHARD + s) * CAP;
        for (int j = 0; j < 110; ++j) {
            const unsigned int v = s_ref[e * 110 + j];
            if (v != SENT && (int)((v >> 23) & 7u) == s) {
                if (pos < CAP) dst[pos] = v;
                ++pos;
            }
        }
    }
}

// ---- K3: per-shard gather + dot + softplus ----
__global__ __launch_bounds__(BLK) void shard_gather(
    const unsigned short* __restrict__ tab,   // f16 [n_tok][128]
    const unsigned int*   __restrict__ cen,   // f16 [batch][64] (uint-packed)
    const unsigned int*   __restrict__ ents,
    const int*            __restrict__ cnts,
    float*                __restrict__ parts)
{
    const int bid = blockIdx.x;
    const int c = bid >> 3, x = bid & 7;      // shard = bid%8 -> XCD affinity
    const int tid = threadIdx.x;
    const int g  = tid >> 4;                  // 16 groups of 16 lanes
    const int gl = tid & 15;

    __shared__ unsigned int lds_c[CHUNK][68]; // padded: breaks bank aliasing
    __shared__ float        s_acc[16][CHUNK];
    __shared__ unsigned int s_list[CAP];

    for (int i = tid; i < 16 * CHUNK; i += BLK)
        (&s_acc[0][0])[i] = 0.0f;

    const int count = cnts[c * NSHARD + x];
    const int npass = (count + 63) >> 6;
    const int total = npass * 64;             // <= CAP (704 = 11*64)

    // stage list (coalesced) with weight-0 dummy padding
    {
        const unsigned int* lg = ents + ((size_t)c * NSHARD + x) * CAP;
        for (int i = tid; i < total; i += BLK)
            s_list[i] = (i < count) ? lg[i] : DUMMY;
    }

    // stage 32 center rows (256 B each): 8 threads/row x 32 B
    {
        const int e = tid >> 3, q = tid & 7;
        const uint4* src = reinterpret_cast<const uint4*>(
            cen + ((size_t)(c * CHUNK + e)) * (D_DIM / 2)) + q * 2;
        const uint4 v0 = src[0];
        const uint4 v1 = src[1];
        *reinterpret_cast<uint4*>(&lds_c[e][q * 8])     = v0;
        *reinterpret_cast<uint4*>(&lds_c[e][q * 8 + 4]) = v1;
    }
    __syncthreads();

    for (int p = 0; p < npass; ++p) {
        const int base = p * 64;
        unsigned int v[4];
        uint4 tv[4];
#pragma unroll
        for (int q = 0; q < 4; ++q)
            v[q] = s_list[base + q * 16 + g];
#pragma unroll
        for (int q = 0; q < 4; ++q)
            tv[q] = *(reinterpret_cast<const uint4*>(
                tab + (size_t)(v[q] & 0x1FFFFu) * D_DIM) + gl);
#pragma unroll
        for (int q = 0; q < 4; ++q) {
            const unsigned int vq = v[q];
            const int elem = (int)((vq >> 17) & 31u);
            const uint4 cv = *reinterpret_cast<const uint4*>(
                &lds_c[elem][gl * 4]);

            float s = dot2acc(tv[q].x, cv.x, 0.0f);
            s = dot2acc(tv[q].y, cv.y, s);
            s = dot2acc(tv[q].z, cv.z, s);
            s = dot2acc(tv[q].w, cv.w, s);
            s += __shfl_xor(s, 8, 64);
            s += __shfl_xor(s, 4, 64);
            s += __shfl_xor(s, 2, 64);
            s += __shfl_xor(s, 1, 64);

            const float xin  = (vq & (1u << 22)) ? s : -s;
            const float wgt  = (vq & (1u << 26)) ? 0.0f : 1.0f;
            const float term = wgt * fast_softplus(xin);
            if (gl == 0) s_acc[g][elem] += term;   // exclusive -> deterministic
        }
    }
    __syncthreads();

    if (tid < CHUNK) {
        float tsum = 0.0f;
#pragma unroll
        for (int gg = 0; gg < 16; ++gg) tsum += s_acc[gg][tid];  // fixed order
        parts[((size_t)c * NSHARD + x) * CHUNK + tid] = tsum;
    }
}

// ---- K4: combine shard partials (fixed order) ----
__global__ __launch_bounds__(BLK) void reduce_out(
    const float* __restrict__ parts, float* __restrict__ out, int batch)
{
    const int b = blockIdx.x * BLK + threadIdx.x;
    if (b >= batch) return;
    const int c = b >> 5, e = b & 31;
    float t = 0.0f;
#pragma unroll
    for (int x = 0; x < NSHARD; ++x)
        t += parts[((size_t)c * NSHARD + x) * CHUNK + e];
    out[b] = t;
}

// ---- fallback: round-3 proven f32 kernel ----
#define NROWS   110
#define NROWS_P 112
#define NPASS   7
__global__ __launch_bounds__(BLK) void w2v_f32_kernel(
    const float* __restrict__ center_vectors,
    const float* __restrict__ outside_vectors,
    const int*   __restrict__ center_word_index,
    const int*   __restrict__ outside_word_indices,
    const int*   __restrict__ negative_samples,
    float*       __restrict__ out)
{
    const int b    = blockIdx.x;
    const int tid  = threadIdx.x;
    const int wave = tid >> 6;
    const int lane = tid & 63;
    const int grp  = lane >> 4;
    const int gl   = lane & 15;

    __shared__ int   s_idx[NROWS_P];
    __shared__ float s_part[4];

    if (tid < W_CTX) {
        s_idx[tid * 11] = outside_word_indices[b * W_CTX + tid];
    } else if (tid >= 16 && tid < 16 + W_CTX * K_NEG) {
        const int r = tid - 16;
        const int w = r / K_NEG;
        const int j = r - w * K_NEG;
        s_idx[w * 11 + 1 + j] = negative_samples[b * W_CTX * K_NEG + r];
    } else if (tid >= 128 && tid < 128 + (NROWS_P - NROWS)) {
        s_idx[NROWS + (tid - 128)] = 0;
    }
    __syncthreads();

    const int ci = center_word_index[b];
    const float4* cp = reinterpret_cast<const float4*>(
        center_vectors + (size_t)ci * D_DIM);
    const float4 c0 = cp[gl];
    const float4 c1 = cp[16 + gl];

    float acc = 0.0f;
#pragma unroll
    for (int p = 0; p < NPASS; ++p) {
        const int r = p * 16 + wave * 4 + grp;
        const int w = r / 11;
        const int j = r - w * 11;
        const int idx = s_idx[r];
        const int oi = s_idx[w * 11];
        const float cf = (oi != 0) ? ((j == 0) ? -1.0f : 1.0f) : 0.0f;

        const float4* rp = reinterpret_cast<const float4*>(
            outside_vectors + (size_t)idx * D_DIM);
        const float4 a0 = rp[gl];
        const float4 a1 = rp[16 + gl];

        float s = c0.x * a0.x;
        s = fmaf(c0.y, a0.y, s);
        s = fmaf(c0.z, a0.z, s);
        s = fmaf(c0.w, a0.w, s);
        s = fmaf(c1.x, a1.x, s);
        s = fmaf(c1.y, a1.y, s);
        s = fmaf(c1.z, a1.z, s);
        s = fmaf(c1.w, a1.w, s);

        s += __shfl_xor(s, 8, 64);
        s += __shfl_xor(s, 4, 64);
        s += __shfl_xor(s, 2, 64);
        s += __shfl_xor(s, 1, 64);

        acc += fabsf(cf) * fast_softplus(cf * s);
    }

    acc += __shfl_xor(acc, 16, 64);
    acc += __shfl_xor(acc, 32, 64);

    if (lane == 0) s_part[wave] = acc;
    __syncthreads();

    if (tid == 0)
        out[b] = s_part[0] + s_part[1] + s_part[2] + s_part[3];
}

extern "C" void kernel_launch(void* const* d_in, const int* in_sizes, int n_in,
                              void* d_out, int out_size, void* d_ws, size_t ws_size,
                              hipStream_t stream) {
    const float* center_vectors       = (const float*)d_in[0];
    const float* outside_vectors      = (const float*)d_in[1];
    const int*   center_word_index    = (const int*)d_in[2];
    const int*   outside_word_indices = (const int*)d_in[3];
    const int*   negative_samples     = (const int*)d_in[4];
    float*       out                  = (float*)d_out;

    const int batch = in_sizes[2];               // 8192
    const int n_tok = in_sizes[1] / D_DIM;       // 100000

    const int nchunk = batch / CHUNK;
    auto al = [](size_t v) { return (v + 255) & ~(size_t)255; };
    const size_t tab_b = al((size_t)n_tok * D_DIM * 2);
    const size_t cen_b = al((size_t)batch * D_DIM * 2);
    const size_t ent_b = al((size_t)nchunk * NSHARD * CAP * 4);
    const size_t cnt_b = al((size_t)nchunk * NSHARD * 4);
    const size_t par_b = al((size_t)nchunk * NSHARD * CHUNK * 4);
    const size_t need  = tab_b + cen_b + ent_b + cnt_b + par_b;

    if ((batch % CHUNK) == 0 && n_tok <= 131072 && ws_size >= need) {
        char* w = (char*)d_ws;
        unsigned short* tab  = (unsigned short*)w;              w += tab_b;
        unsigned int*   cen  = (unsigned int*)w;                w += cen_b;
        unsigned int*   ents = (unsigned int*)w;                w += ent_b;
        int*            cnts = (int*)w;                         w += cnt_b;
        float*          part = (float*)w;

        const float inv_shard = 1.0f / (float)((n_tok + NSHARD - 1) / NSHARD);

        const int n8 = n_tok * D_DIM / 8;
        cvt_table_f16<<<(n8 + BLK - 1) / BLK, BLK, 0, stream>>>(
            (const float4*)outside_vectors, (uint4*)tab, n8);
        cvt_centers_f16<<<(batch + 3) / 4, BLK, 0, stream>>>(
            center_vectors, center_word_index, cen, batch);
        bucketize<<<nchunk, BLK, 0, stream>>>(
            outside_word_indices, negative_samples, ents, cnts, inv_shard);
        shard_gather<<<nchunk * NSHARD, BLK, 0, stream>>>(
            tab, cen, ents, cnts, part);
        reduce_out<<<(batch + BLK - 1) / BLK, BLK, 0, stream>>>(
            part, out, batch);
    } else {
        w2v_f32_kernel<<<batch, BLK, 0, stream>>>(
            center_vectors, outside_vectors, center_word_index,
            outside_word_indices, negative_samples, out);
    }
}

// Round 12
// 48.805 us; speedup vs baseline: 1.7803x; 1.4084x over previous
//
#include <hip/hip_runtime.h>

// NegSamplingWord2Vec, traffic-optimized (bf16 gather table) — round-7 revert:
//   losses[b] = sum_w mask(o_idx!=PAD) * ( softplus(-dot(c,o_w)) +
//                                          sum_k softplus(dot(c,neg_wk)) )
//
// Best measured variant (48.9 us). Two stages, both at measured ceilings:
//  1) convert_bf16: f32 table -> bf16 table in ws. 77 MB streaming at the
//     ~6.9 TB/s fill ceiling  (~11 us).
//  2) gather: 8192 blocks x 256 thr; 110 rows/elem as 16-lane groups x 7
//     passes; 256 B bf16 rows, fully coalesced. ~137 MB compulsory
//     per-XCD-unique random-line traffic at the ~3.4 TB/s beyond-L2
//     ceiling (~36 us).
// Sharding (R10/R11) and extra MLP (R8) empirically refuted; fp8 refuted
// by error budget (bf16 absmax 4.0 x ~32 >> threshold 17.2).

#define D_DIM   128
#define W_CTX   10
#define K_NEG   10
#define NROWS   110
#define NROWS_P 112
#define NPASS   7
#define BLK     256

__device__ __forceinline__ float fast_softplus(float x) {
    // log(1+exp(x)) via hw v_exp_f32 / v_log_f32
    return fmaxf(x, 0.0f) + __logf(1.0f + __expf(-fabsf(x)));
}

__device__ __forceinline__ unsigned short bf16_rne(float f) {
    unsigned int x = __float_as_uint(f);
    x += 0x7fffu + ((x >> 16) & 1u);
    return (unsigned short)(x >> 16);
}
__device__ __forceinline__ float bflo(unsigned int u) {
    return __uint_as_float(u << 16);
}
__device__ __forceinline__ float bfhi(unsigned int u) {
    return __uint_as_float(u & 0xffff0000u);
}

// ---- kernel 1: f32 table -> bf16 table (RNE), fully streaming ----
__global__ __launch_bounds__(256) void convert_bf16_kernel(
    const float4* __restrict__ src, ushort4* __restrict__ dst, int n4)
{
    const int i = blockIdx.x * 256 + threadIdx.x;
    if (i < n4) {
        const float4 v = src[i];
        ushort4 o;
        o.x = bf16_rne(v.x);
        o.y = bf16_rne(v.y);
        o.z = bf16_rne(v.z);
        o.w = bf16_rne(v.w);
        dst[i] = o;
    }
}

// ---- kernel 2: gather bf16 rows + dot + softplus ----
__global__ __launch_bounds__(BLK) void w2v_bf16_kernel(
    const float*          __restrict__ center_vectors,
    const unsigned short* __restrict__ outside_bf16,
    const int*            __restrict__ center_word_index,
    const int*            __restrict__ outside_word_indices,
    const int*            __restrict__ negative_samples,
    float*                __restrict__ out)
{
    const int b    = blockIdx.x;
    const int tid  = threadIdx.x;
    const int wave = tid >> 6;
    const int lane = tid & 63;
    const int grp  = lane >> 4;   // 0..3 row-group within wave
    const int gl   = lane & 15;   // lane within 16-lane row group

    __shared__ int   s_idx[NROWS_P];
    __shared__ float s_part[4];

    // stage row indices into LDS (slot w*11 = positive/oidx)
    if (tid < W_CTX) {
        s_idx[tid * 11] = outside_word_indices[b * W_CTX + tid];
    } else if (tid >= 16 && tid < 16 + W_CTX * K_NEG) {
        const int r = tid - 16;                   // 0..99, coalesced
        const int w = r / K_NEG;
        const int j = r - w * K_NEG;
        s_idx[w * 11 + 1 + j] = negative_samples[b * W_CTX * K_NEG + r];
    } else if (tid >= 128 && tid < 128 + (NROWS_P - NROWS)) {
        s_idx[NROWS + (tid - 128)] = 0;           // pad rows -> row 0
    }
    __syncthreads();

    // center fragment: elements [gl*8, gl*8+8) as two contiguous float4
    const int ci = center_word_index[b];
    const float4* cp = reinterpret_cast<const float4*>(
        center_vectors + (size_t)ci * D_DIM);
    const float4 c0 = cp[gl * 2];
    const float4 c1 = cp[gl * 2 + 1];

    // my 7 row ids + coefficients
    int   idxs[NPASS];
    float cfs[NPASS];
#pragma unroll
    for (int p = 0; p < NPASS; ++p) {
        const int r = p * 16 + wave * 4 + grp;    // unique row in [0,112)
        const int w = r / 11;
        const int j = r - w * 11;
        idxs[p] = s_idx[r];
        const int oi = s_idx[w * 11];             // positive slot = oidx
        cfs[p] = (oi != 0) ? ((j == 0) ? -1.0f : 1.0f) : 0.0f;
    }

    // issue all 7 row loads (16 B each: 8 bf16 = elems [gl*8, gl*8+8))
    uint4 rv[NPASS];
#pragma unroll
    for (int p = 0; p < NPASS; ++p) {
        rv[p] = reinterpret_cast<const uint4*>(
            outside_bf16 + (size_t)idxs[p] * D_DIM)[gl];
    }
    // loads cannot sink past a may-write-memory asm; all 7 stay in flight
    asm volatile("" ::: "memory");
    __builtin_amdgcn_sched_barrier(0);

    float acc = 0.0f;
#pragma unroll
    for (int p = 0; p < NPASS; ++p) {
        float s = c0.x * bflo(rv[p].x);
        s = fmaf(c0.y, bfhi(rv[p].x), s);
        s = fmaf(c0.z, bflo(rv[p].y), s);
        s = fmaf(c0.w, bfhi(rv[p].y), s);
        s = fmaf(c1.x, bflo(rv[p].z), s);
        s = fmaf(c1.y, bfhi(rv[p].z), s);
        s = fmaf(c1.z, bflo(rv[p].w), s);
        s = fmaf(c1.w, bfhi(rv[p].w), s);

        s += __shfl_xor(s, 8, 64);
        s += __shfl_xor(s, 4, 64);
        s += __shfl_xor(s, 2, 64);
        s += __shfl_xor(s, 1, 64);

        acc += fabsf(cfs[p]) * fast_softplus(cfs[p] * s);
    }

    acc += __shfl_xor(acc, 16, 64);
    acc += __shfl_xor(acc, 32, 64);

    if (lane == 0) s_part[wave] = acc;
    __syncthreads();

    if (tid == 0)
        out[b] = s_part[0] + s_part[1] + s_part[2] + s_part[3];
}

// ---- fallback (round-3 proven f32 kernel) if ws too small ----
__global__ __launch_bounds__(BLK) void w2v_f32_kernel(
    const float* __restrict__ center_vectors,
    const float* __restrict__ outside_vectors,
    const int*   __restrict__ center_word_index,
    const int*   __restrict__ outside_word_indices,
    const int*   __restrict__ negative_samples,
    float*       __restrict__ out)
{
    const int b    = blockIdx.x;
    const int tid  = threadIdx.x;
    const int wave = tid >> 6;
    const int lane = tid & 63;
    const int grp  = lane >> 4;
    const int gl   = lane & 15;

    __shared__ int   s_idx[NROWS_P];
    __shared__ float s_part[4];

    if (tid < W_CTX) {
        s_idx[tid * 11] = outside_word_indices[b * W_CTX + tid];
    } else if (tid >= 16 && tid < 16 + W_CTX * K_NEG) {
        const int r = tid - 16;
        const int w = r / K_NEG;
        const int j = r - w * K_NEG;
        s_idx[w * 11 + 1 + j] = negative_samples[b * W_CTX * K_NEG + r];
    } else if (tid >= 128 && tid < 128 + (NROWS_P - NROWS)) {
        s_idx[NROWS + (tid - 128)] = 0;
    }
    __syncthreads();

    const int ci = center_word_index[b];
    const float4* cp = reinterpret_cast<const float4*>(
        center_vectors + (size_t)ci * D_DIM);
    const float4 c0 = cp[gl];
    const float4 c1 = cp[16 + gl];

    float acc = 0.0f;
#pragma unroll
    for (int p = 0; p < NPASS; ++p) {
        const int r = p * 16 + wave * 4 + grp;
        const int w = r / 11;
        const int j = r - w * 11;
        const int idx = s_idx[r];
        const int oi = s_idx[w * 11];
        const float cf = (oi != 0) ? ((j == 0) ? -1.0f : 1.0f) : 0.0f;

        const float4* rp = reinterpret_cast<const float4*>(
            outside_vectors + (size_t)idx * D_DIM);
        const float4 a0 = rp[gl];
        const float4 a1 = rp[16 + gl];

        float s = c0.x * a0.x;
        s = fmaf(c0.y, a0.y, s);
        s = fmaf(c0.z, a0.z, s);
        s = fmaf(c0.w, a0.w, s);
        s = fmaf(c1.x, a1.x, s);
        s = fmaf(c1.y, a1.y, s);
        s = fmaf(c1.z, a1.z, s);
        s = fmaf(c1.w, a1.w, s);

        s += __shfl_xor(s, 8, 64);
        s += __shfl_xor(s, 4, 64);
        s += __shfl_xor(s, 2, 64);
        s += __shfl_xor(s, 1, 64);

        acc += fabsf(cf) * fast_softplus(cf * s);
    }

    acc += __shfl_xor(acc, 16, 64);
    acc += __shfl_xor(acc, 32, 64);

    if (lane == 0) s_part[wave] = acc;
    __syncthreads();

    if (tid == 0)
        out[b] = s_part[0] + s_part[1] + s_part[2] + s_part[3];
}

extern "C" void kernel_launch(void* const* d_in, const int* in_sizes, int n_in,
                              void* d_out, int out_size, void* d_ws, size_t ws_size,
                              hipStream_t stream) {
    const float* center_vectors       = (const float*)d_in[0];
    const float* outside_vectors      = (const float*)d_in[1];
    const int*   center_word_index    = (const int*)d_in[2];
    const int*   outside_word_indices = (const int*)d_in[3];
    const int*   negative_samples     = (const int*)d_in[4];
    float*       out                  = (float*)d_out;

    const int batch    = in_sizes[2];             // 8192
    const int n_tokens = in_sizes[1] / D_DIM;     // 100000
    const size_t need  = (size_t)n_tokens * D_DIM * sizeof(unsigned short);

    if (ws_size >= need) {
        unsigned short* obf = (unsigned short*)d_ws;
        const int n4 = n_tokens * D_DIM / 4;      // 3.2M float4 groups
        convert_bf16_kernel<<<(n4 + 255) / 256, 256, 0, stream>>>(
            (const float4*)outside_vectors, (ushort4*)obf, n4);
        w2v_bf16_kernel<<<batch, BLK, 0, stream>>>(
            center_vectors, obf, center_word_index,
            outside_word_indices, negative_samples, out);
    } else {
        w2v_f32_kernel<<<batch, BLK, 0, stream>>>(
            center_vectors, outside_vectors, center_word_index,
            outside_word_indices, negative_samples, out);
    }
}